// Round 3
// baseline (336.842 us; speedup 1.0000x reference)
//
#include <hip/hip_runtime.h>
#include <hip/hip_bf16.h>

#define B_ 256
#define L_ 225
#define D_ 1280
#define H_ 256
#define U_ 256
#define LT 32
#define NFT 7    // 7 full tiles = rows 0..223; row 224 handled by tail path

typedef __bf16  bf16x8 __attribute__((ext_vector_type(8)));
typedef float   f32x4  __attribute__((ext_vector_type(4)));
typedef unsigned short u16x8 __attribute__((ext_vector_type(8)));
typedef unsigned short u16x4 __attribute__((ext_vector_type(4)));

__device__ __forceinline__ unsigned short f2bf(float f) {
    union { __hip_bfloat16 h; unsigned short u; } cv;
    cv.h = __float2bfloat16(f);   // RNE
    return cv.u;
}

__device__ __forceinline__ f32x4 bf4_to_f32(u16x4 w) {
    union { unsigned u; float f; } a0, a1, a2, a3;
    a0.u = (unsigned)w[0] << 16; a1.u = (unsigned)w[1] << 16;
    a2.u = (unsigned)w[2] << 16; a3.u = (unsigned)w[3] << 16;
    return (f32x4){a0.f, a1.f, a2.f, a3.f};
}

__device__ __forceinline__ void gload_lds16(const void* g, void* l) {
    __builtin_amdgcn_global_load_lds(
        (const __attribute__((address_space(1))) unsigned int*)g,
        (__attribute__((address_space(3))) unsigned int*)l,
        16, 0, 0);
}

__device__ __forceinline__ float wredmax(float x) {
#pragma unroll
    for (int off = 32; off > 0; off >>= 1) x = fmaxf(x, __shfl_xor(x, off, 64));
    return x;
}
__device__ __forceinline__ float wredsum(float x) {
#pragma unroll
    for (int off = 32; off > 0; off >>= 1) x += __shfl_xor(x, off, 64);
    return x;
}

// ---------------- kernel 1: W1 [D][U] f32 -> W1t [U][D] bf16 ----------------
__global__ void k_prep_w1t(const float* __restrict__ W1, __hip_bfloat16* __restrict__ w1t) {
    int idx = blockIdx.x * 256 + threadIdx.x;   // idx = k*U_+u
    int k = idx / U_;
    int u = idx % U_;
    w1t[(size_t)u * D_ + k] = __float2bfloat16(W1[idx]);
}

// ------------- kernel 2: ph[b][u] = hidden[b].W2[:,u] + b1[u] + b2[u] -------
__global__ void k_proj_h(const float* __restrict__ hidden, const float* __restrict__ W2,
                         const float* __restrict__ b1, const float* __restrict__ b2,
                         float* __restrict__ ph) {
    __shared__ float sh[H_];
    int b = blockIdx.x;
    int u = threadIdx.x;
    sh[u] = hidden[b * H_ + u];
    __syncthreads();
    float acc = b1[u] + b2[u];
#pragma unroll 8
    for (int h = 0; h < H_; ++h) acc += sh[h] * W2[h * U_ + u];
    ph[b * U_ + u] = acc;
}

// ------- stage one K-slice of W1t [256 u][64 k] bf16 into LDS (swizzled) ----
__device__ __forceinline__ void stageB(const __hip_bfloat16* __restrict__ w1t,
                                       char* buf, int kt, int tid) {
#pragma unroll
    for (int pass = 0; pass < 2; ++pass) {
        int s   = pass * 1024 + tid;
        int u   = s >> 3;
        int c8s = s & 7;
        int c8g = c8s ^ (u & 7);
        gload_lds16(w1t + (size_t)u * D_ + kt * 64 + c8g * 8, buf + s * 16);
    }
}

// ---------------- kernel 3: fused flash-style per-batch kernel --------------
// 256 blocks x 1024 threads. Per L-tile of 32 rows: stage f32->bf16 tile in
// LDS, GEMM vs W1t (K-streamed dbuf), logits -> online softmax -> context
// accumulated from the LDS tile. features read from HBM exactly once.
// LDS: sA [32][2560B] @0 (81920) | sB dbuf 2x32768 @81920 | sV @147456
//      sPh @148480 | sLp @149504 (1KB) | sW @150528 | sSc @150656
__global__ __launch_bounds__(1024, 4) void k_fused(
        const float* __restrict__ feat,
        const __hip_bfloat16* __restrict__ w1t,
        const float* __restrict__ ph,
        const float* __restrict__ Vv,
        float* __restrict__ out) {
    __shared__ __align__(128) char smem[150784];
    char*  sB  = smem + 81920;
    float* sV  = (float*)(smem + 147456);
    float* sPh = (float*)(smem + 148480);
    float* sLp = (float*)(smem + 149504);
    float* sW  = (float*)(smem + 150528);
    float* sSc = (float*)(smem + 150656);

    const int tid  = threadIdx.x;
    const int lane = tid & 63;
    const int wave = tid >> 6;     // 0..15
    const int wr   = wave >> 3;    // 0..1  -> rows [wr*16,+16)
    const int wc   = wave & 7;     // 0..7  -> u-cols [wc*32,+32)
    const int b    = blockIdx.x;

    if (tid < 256) { sV[tid] = Vv[tid]; sPh[tid] = ph[b * 256 + tid]; }

    const float* featB = feat + (size_t)b * L_ * D_;

    f32x4 c[5];
#pragma unroll
    for (int ch = 0; ch < 5; ++ch) c[ch] = (f32x4){0.f, 0.f, 0.f, 0.f};
    float m_run = -3.0e38f, s_run = 0.f;   // live in wave 0

    for (int t = 0; t < NFT; ++t) {
        __syncthreads();   // prev tile's context reads of sA done; sB free

        // ---- stage A tile: 32 rows x 1280, f32 -> bf16, swizzled ----
#pragma unroll
        for (int p = 0; p < 10; ++p) {
            int idx = tid + p * 1024;          // f32x4 index, 10240 total
            int r   = idx / 320;
            int c4  = idx - r * 320;
            f32x4 v = *reinterpret_cast<const f32x4*>(
                featB + (size_t)(t * LT + r) * D_ + c4 * 4);
            u16x4 w;
            w[0] = f2bf(v[0]); w[1] = f2bf(v[1]); w[2] = f2bf(v[2]); w[3] = f2bf(v[3]);
            *reinterpret_cast<u16x4*>(smem + r * 2560 + ((c4 * 8) ^ ((r & 7) << 4))) = w;
        }
        stageB(w1t, sB, 0, tid);
        __syncthreads();

        // ---- GEMM: 20 K-steps of 64, B double-buffered ----
        f32x4 acc0 = (f32x4){0.f, 0.f, 0.f, 0.f};
        f32x4 acc1 = (f32x4){0.f, 0.f, 0.f, 0.f};
        int cur = 0;
        const int r  = wr * 16 + (lane & 15);
        const int u0 = wc * 32 + (lane & 15);
        const int aswz = (r & 7) << 4;
        const int bswz = (u0 & 7) << 4;
        for (int kt = 0; kt < 20; ++kt) {
            if (kt < 19) stageB(w1t, sB + (cur ^ 1) * 32768, kt + 1, tid);
            const char* bufB = sB + cur * 32768;
#pragma unroll
            for (int ks = 0; ks < 2; ++ks) {
                int kloc = ks * 64 + ((lane >> 4) << 4);   // byte offset in 128B row
                bf16x8 a = *reinterpret_cast<const bf16x8*>(
                    smem + r * 2560 + ((kt * 128 + kloc) ^ aswz));
                bf16x8 b0 = *reinterpret_cast<const bf16x8*>(
                    bufB + u0 * 128 + (kloc ^ bswz));
                bf16x8 b1 = *reinterpret_cast<const bf16x8*>(
                    bufB + (u0 + 16) * 128 + (kloc ^ bswz));
                acc0 = __builtin_amdgcn_mfma_f32_16x16x32_bf16(a, b0, acc0, 0, 0, 0);
                acc1 = __builtin_amdgcn_mfma_f32_16x16x32_bf16(a, b1, acc1, 0, 0, 0);
            }
            __syncthreads();
            cur ^= 1;
        }

        // ---- epilogue: tanh(acc+ph)*V, partial logits ----
        float ph0 = sPh[u0], ph1 = sPh[u0 + 16];
        float v0  = sV[u0],  v1  = sV[u0 + 16];
#pragma unroll
        for (int rg = 0; rg < 4; ++rg) {
            int row = wr * 16 + ((lane >> 4) << 2) + rg;   // 0..31
            float x0 = acc0[rg] + ph0;
            float x1 = acc1[rg] + ph1;
            float sl = (1.f - 2.f / (__expf(2.f * x0) + 1.f)) * v0
                     + (1.f - 2.f / (__expf(2.f * x1) + 1.f)) * v1;
            sl += __shfl_xor(sl, 1, 64);
            sl += __shfl_xor(sl, 2, 64);
            sl += __shfl_xor(sl, 4, 64);
            sl += __shfl_xor(sl, 8, 64);
            if ((lane & 15) == 0) sLp[wc * 32 + row] = sl;
        }
        __syncthreads();

        // ---- online softmax update (wave 0) ----
        if (wave == 0) {
            float lg = -3.0e38f;
            if (lane < 32) {
                lg = 0.f;
#pragma unroll
                for (int w8 = 0; w8 < 8; ++w8) lg += sLp[w8 * 32 + lane];
            }
            float tmax = wredmax(lg);
            float nm   = fmaxf(m_run, tmax);
            float wv   = (lane < 32) ? __expf(lg - nm) : 0.f;
            float ts   = wredsum(wv);
            float rs   = __expf(m_run - nm);
            s_run = s_run * rs + ts;
            m_run = nm;
            if (lane < 32) sW[lane] = wv;
            if (lane == 0) sSc[0] = rs;
        }
        __syncthreads();

        // ---- context accumulate from LDS bf16 tile ----
        float rs = sSc[0];
#pragma unroll
        for (int ch = 0; ch < 5; ++ch) c[ch] *= rs;
#pragma unroll
        for (int rp = 0; rp < 2; ++rp) {
            int rr = wave + rp * 16;
            float wgt = sW[rr];
            const char* arow = smem + rr * 2560;
            int rswz = (rr & 7) << 4;
#pragma unroll
            for (int ch = 0; ch < 5; ++ch) {
                u16x4 w4 = *reinterpret_cast<const u16x4*>(
                    arow + ((ch * 512 + lane * 8) ^ rswz));
                c[ch] += wgt * bf4_to_f32(w4);
            }
        }
    }

    // ---- tail: row 224 logit (VALU dot) + online update + accumulate ----
    {
        const float* frow = featB + (size_t)224 * D_;
        int u  = wave * 16 + (lane & 15);
        int kq = lane >> 4;
        const float* fk = frow + kq * 320;
        const __hip_bfloat16* wk = w1t + (size_t)u * D_ + kq * 320;
        float dot = 0.f;
#pragma unroll 8
        for (int i = 0; i < 80; ++i) {
            f32x4 fv = *reinterpret_cast<const f32x4*>(fk + i * 4);
            u16x4 w4 = *reinterpret_cast<const u16x4*>(wk + i * 4);
            f32x4 wf = bf4_to_f32(w4);
            dot += fv[0] * wf[0] + fv[1] * wf[1] + fv[2] * wf[2] + fv[3] * wf[3];
        }
        dot += __shfl_xor(dot, 16, 64);
        dot += __shfl_xor(dot, 32, 64);
        float xg = dot + sPh[u];
        float sv = (1.f - 2.f / (__expf(2.f * xg) + 1.f)) * sV[u];
        sv += __shfl_xor(sv, 1, 64);
        sv += __shfl_xor(sv, 2, 64);
        sv += __shfl_xor(sv, 4, 64);
        sv += __shfl_xor(sv, 8, 64);
        if (lane == 0) sLp[wave] = sv;
    }
    __syncthreads();
    if (wave == 0) {
        float lg = 0.f;
#pragma unroll
        for (int i = 0; i < 16; ++i) lg += sLp[i];
        float nm = fmaxf(m_run, lg);
        float wv = __expf(lg - nm);
        float rs = __expf(m_run - nm);
        s_run = s_run * rs + wv;
        if (lane == 0) { sSc[0] = rs; sSc[1] = s_run; sW[0] = wv; }
    }
    __syncthreads();
    {
        float rs = sSc[0];
#pragma unroll
        for (int ch = 0; ch < 5; ++ch) c[ch] *= rs;
        if (wave == 0) {
            float wgt = sW[0];
            const float* frow = featB + (size_t)224 * D_;
#pragma unroll
            for (int ch = 0; ch < 5; ++ch)
                c[ch] += wgt * *reinterpret_cast<const f32x4*>(frow + ch * 256 + lane * 4);
        }
    }

    // ---- final: reduce 16 wave partials, divide by s, write out ----
    __syncthreads();   // sA region free now
    float* pc = (float*)smem;   // [16][1280] f32
#pragma unroll
    for (int ch = 0; ch < 5; ++ch)
        *reinterpret_cast<f32x4*>(pc + wave * 1280 + ch * 256 + (lane << 2)) = c[ch];
    __syncthreads();
    if (tid < 320) {
        f32x4 s = (f32x4){0.f, 0.f, 0.f, 0.f};
#pragma unroll
        for (int w = 0; w < 16; ++w)
            s += *reinterpret_cast<const f32x4*>(pc + w * 1280 + (tid << 2));
        float inv = 1.f / sSc[1];
        s *= inv;
        *reinterpret_cast<f32x4*>(out + (size_t)b * D_ + (tid << 2)) = s;
    }
}

extern "C" void kernel_launch(void* const* d_in, const int* in_sizes, int n_in,
                              void* d_out, int out_size, void* d_ws, size_t ws_size,
                              hipStream_t stream) {
    const float* feat   = (const float*)d_in[0];
    const float* hidden = (const float*)d_in[1];
    const float* W1     = (const float*)d_in[2];
    const float* b1     = (const float*)d_in[3];
    const float* W2     = (const float*)d_in[4];
    const float* b2     = (const float*)d_in[5];
    const float* Vv     = (const float*)d_in[6];
    // bV (d_in[7]) is a uniform logit shift -> softmax-invariant; skipped.

    char* ws = (char*)d_ws;
    __hip_bfloat16* w1t = (__hip_bfloat16*)(ws);        // 655360 B
    float* ph = (float*)(ws + 655360);                  // 262144 B
    float* out = (float*)d_out;

    k_prep_w1t<<<(U_ * D_) / 256, 256, 0, stream>>>(W1, w1t);
    k_proj_h  <<<B_, U_, 0, stream>>>(hidden, W2, b1, b2, ph);
    k_fused   <<<B_, 1024, 0, stream>>>(feat, w1t, ph, Vv, out);
}

// Round 4
// 146.745 us; speedup vs baseline: 2.2954x; 2.2954x over previous
//
#include <hip/hip_runtime.h>
#include <hip/hip_bf16.h>

#define B_ 256
#define L_ 225
#define D_ 1280
#define H_ 256
#define U_ 256

typedef __bf16  bf16x8 __attribute__((ext_vector_type(8)));
typedef float   f32x4  __attribute__((ext_vector_type(4)));
typedef unsigned short u16x8 __attribute__((ext_vector_type(8)));
typedef unsigned short u16x4 __attribute__((ext_vector_type(4)));

__device__ __forceinline__ unsigned short f2bf(float f) {
    union { __hip_bfloat16 h; unsigned short u; } cv;
    cv.h = __float2bfloat16(f);   // RNE
    return cv.u;
}

__device__ __forceinline__ f32x4 bf4_to_f32(u16x4 w) {
    union { unsigned u; float f; } a0, a1, a2, a3;
    a0.u = (unsigned)w[0] << 16; a1.u = (unsigned)w[1] << 16;
    a2.u = (unsigned)w[2] << 16; a3.u = (unsigned)w[3] << 16;
    return (f32x4){a0.f, a1.f, a2.f, a3.f};
}

__device__ __forceinline__ void gload_lds16(const void* g, void* l) {
    __builtin_amdgcn_global_load_lds(
        (const __attribute__((address_space(1))) unsigned int*)g,
        (__attribute__((address_space(3))) unsigned int*)l,
        16, 0, 0);
}

__device__ __forceinline__ float wredsum(float x) {
#pragma unroll
    for (int off = 32; off > 0; off >>= 1) x += __shfl_xor(x, off, 64);
    return x;
}

// ---------------- kernel 1: W1 [D][U] f32 -> W1t [U][D] bf16 ----------------
__global__ void k_prep_w1t(const float* __restrict__ W1, __hip_bfloat16* __restrict__ w1t) {
    int idx = blockIdx.x * 256 + threadIdx.x;   // idx = k*U_+u
    int k = idx / U_;
    int u = idx % U_;
    w1t[(size_t)u * D_ + k] = __float2bfloat16(W1[idx]);
}

// ------------- kernel 2: ph[b][u] = hidden[b].W2[:,u] + b1[u] + b2[u] -------
__global__ void k_proj_h(const float* __restrict__ hidden, const float* __restrict__ W2,
                         const float* __restrict__ b1, const float* __restrict__ b2,
                         float* __restrict__ ph) {
    __shared__ float sh[H_];
    int b = blockIdx.x;
    int u = threadIdx.x;
    sh[u] = hidden[b * H_ + u];
    __syncthreads();
    float acc = b1[u] + b2[u];
#pragma unroll 8
    for (int h = 0; h < H_; ++h) acc += sh[h] * W2[h * U_ + u];
    ph[b * U_ + u] = acc;
}

// ---------------- kernel 3: fully fused per-batch kernel --------------------
// 256 blocks (1/CU) x 1024 threads. Block b: GEMM(225pad256 x 256 x 1280) ->
// tanh*V -> exp (no-max softmax) -> context. T14 split staging; optional bf16
// feature side-copy for phase 3 (BF16WS=1).
// LDS: dbuf 2 x 65536 (A 32K swz + B 32K swz) | sV @131072 | sPh @132096
//      sL[4][256] @133120 | sW[256] @137216 | sRed[16] @138240
__global__ __launch_bounds__(1024) void __attribute__((noinline)) k_dummy() {}

template<int BF16WS>
__global__ __launch_bounds__(1024) void k_fused(
        const float* __restrict__ feat,
        const __hip_bfloat16* __restrict__ w1t,
        const float* __restrict__ ph,
        const float* __restrict__ Vv,
        __hip_bfloat16* __restrict__ fbf,
        float* __restrict__ out) {
    __shared__ __align__(128) char smem[138304];
    float* sV   = (float*)(smem + 131072);
    float* sPh  = (float*)(smem + 132096);
    float* sL   = (float*)(smem + 133120);
    float* sW   = (float*)(smem + 137216);
    float* sRed = (float*)(smem + 138240);

    const int tid  = threadIdx.x;
    const int lane = tid & 63;
    const int wave = tid >> 6;     // 0..15
    const int wr   = wave >> 2;    // rows [wr*64, +64)
    const int wc   = wave & 3;     // cols [wc*64, +64)
    const int b    = blockIdx.x;

    if (tid < 256) { sV[tid] = Vv[tid]; sPh[tid] = ph[b * 256 + tid]; }

    // A staging map: thread -> (row ar, 16-float k-chunk)
    const int ar    = tid >> 2;                  // 0..255
    const int arc   = ar < L_ ? ar : (L_ - 1);   // clamp padded rows
    const int akseg = (tid & 3) << 4;            // 0,16,32,48
    const float* aSrc0 = feat + ((size_t)(b * L_ + arc) * D_ + akseg);
    __hip_bfloat16* fDst0 = fbf + ((size_t)(b * L_ + arc) * D_ + akseg);
    const int ac80 = akseg >> 3;
    const int aswz = (ar & 7) << 4;

    f32x4 acc[4][4];
#pragma unroll
    for (int mi = 0; mi < 4; ++mi)
#pragma unroll
        for (int ni = 0; ni < 4; ++ni)
            acc[mi][ni] = (f32x4){0.f, 0.f, 0.f, 0.f};

    auto loadA = [&](int kt, f32x4* v) {
        const float* src = aSrc0 + kt * 64;
        v[0] = *reinterpret_cast<const f32x4*>(src);
        v[1] = *reinterpret_cast<const f32x4*>(src + 4);
        v[2] = *reinterpret_cast<const f32x4*>(src + 8);
        v[3] = *reinterpret_cast<const f32x4*>(src + 12);
    };
    auto stageB = [&](int kt, char* bufB) {
#pragma unroll
        for (int pass = 0; pass < 2; ++pass) {
            int s   = pass * 1024 + tid;
            int u   = s >> 3;
            int c8s = s & 7;
            int c8g = c8s ^ (u & 7);
            gload_lds16(w1t + (size_t)u * D_ + kt * 64 + c8g * 8, bufB + s * 16);
        }
    };
    auto storeA = [&](int kt, const f32x4* v, char* bufA) {
        u16x8 w0, w1;
        w0[0] = f2bf(v[0][0]); w0[1] = f2bf(v[0][1]); w0[2] = f2bf(v[0][2]); w0[3] = f2bf(v[0][3]);
        w0[4] = f2bf(v[1][0]); w0[5] = f2bf(v[1][1]); w0[6] = f2bf(v[1][2]); w0[7] = f2bf(v[1][3]);
        w1[0] = f2bf(v[2][0]); w1[1] = f2bf(v[2][1]); w1[2] = f2bf(v[2][2]); w1[3] = f2bf(v[2][3]);
        w1[4] = f2bf(v[3][0]); w1[5] = f2bf(v[3][1]); w1[6] = f2bf(v[3][2]); w1[7] = f2bf(v[3][3]);
        *reinterpret_cast<u16x8*>(bufA + (ar << 7) + ((ac80 << 4) ^ aswz))       = w0;
        *reinterpret_cast<u16x8*>(bufA + (ar << 7) + (((ac80 + 1) << 4) ^ aswz)) = w1;
        if (BF16WS && ar < L_) {
            *reinterpret_cast<u16x8*>(fDst0 + kt * 64)     = w0;
            *reinterpret_cast<u16x8*>(fDst0 + kt * 64 + 8) = w1;
        }
    };
    auto compute = [&](const char* bufA, const char* bufB) {
#pragma unroll
        for (int ks = 0; ks < 2; ++ks) {
            const int kk2 = (ks * 32 + ((lane >> 4) << 3)) * 2;
            bf16x8 a[4], bb[4];
#pragma unroll
            for (int mi = 0; mi < 4; ++mi) {
                int r = wr * 64 + mi * 16 + (lane & 15);
                a[mi] = *reinterpret_cast<const bf16x8*>(bufA + (r << 7) + (kk2 ^ ((r & 7) << 4)));
            }
#pragma unroll
            for (int ni = 0; ni < 4; ++ni) {
                int u = wc * 64 + ni * 16 + (lane & 15);
                bb[ni] = *reinterpret_cast<const bf16x8*>(bufB + (u << 7) + (kk2 ^ ((u & 7) << 4)));
            }
#pragma unroll
            for (int mi = 0; mi < 4; ++mi)
#pragma unroll
                for (int ni = 0; ni < 4; ++ni)
                    acc[mi][ni] = __builtin_amdgcn_mfma_f32_16x16x32_bf16(
                        a[mi], bb[ni], acc[mi][ni], 0, 0, 0);
        }
    };

    // ---- phase 1: K-streamed GEMM, dbuf, T14 split (load early, write late)
    {
        f32x4 v[4];
        loadA(0, v);
        stageB(0, smem + 32768);
        storeA(0, v, smem);
    }
    __syncthreads();
    int cur = 0;
    for (int kt = 0; kt < 20; ++kt) {
        char* bufN = smem + (cur ^ 1) * 65536;
        f32x4 v[4];
        if (kt < 19) { loadA(kt + 1, v); stageB(kt + 1, bufN + 32768); }
        char* bufC = smem + cur * 65536;
        compute(bufC, bufC + 32768);
        if (kt < 19) storeA(kt + 1, v, bufN);
        __syncthreads();
        cur ^= 1;
    }

    // ---- epilogue: tanh(acc+ph)*V -> logits; w = exp(logit) (no max) ----
    float phu[4], vu[4];
#pragma unroll
    for (int ni = 0; ni < 4; ++ni) {
        int u = wc * 64 + ni * 16 + (lane & 15);
        phu[ni] = sPh[u];
        vu[ni]  = sV[u];
    }
#pragma unroll
    for (int mi = 0; mi < 4; ++mi) {
#pragma unroll
        for (int rg = 0; rg < 4; ++rg) {
            int row = wr * 64 + mi * 16 + ((lane >> 4) << 2) + rg;
            float s = 0.f;
#pragma unroll
            for (int ni = 0; ni < 4; ++ni) {
                float x = acc[mi][ni][rg] + phu[ni];
                s += (1.f - 2.f / (__expf(2.f * x) + 1.f)) * vu[ni];
            }
            s += __shfl_xor(s, 1, 64);
            s += __shfl_xor(s, 2, 64);
            s += __shfl_xor(s, 4, 64);
            s += __shfl_xor(s, 8, 64);
            if ((lane & 15) == 0) sL[wc * 256 + row] = s;
        }
    }
    __syncthreads();
    float den_p = 0.f;
    if (tid < 256) {
        float lg = sL[tid] + sL[256 + tid] + sL[512 + tid] + sL[768 + tid];
        float w  = (tid < L_) ? __expf(lg) : 0.f;   // |lg| <= sum|V| ~ 13: safe
        sW[tid] = w;
        den_p = w;
    }
    den_p = wredsum(den_p);
    if (lane == 0) sRed[wave] = den_p;
    __syncthreads();

    // ---- phase 3: context = sum_l w_l * feat[b,l,:] ----
    f32x4 c[5];
#pragma unroll
    for (int ch = 0; ch < 5; ++ch) c[ch] = (f32x4){0.f, 0.f, 0.f, 0.f};

    if (BF16WS) {
        const char* fB = (const char*)(fbf + (size_t)b * L_ * D_);
        int l = wave;
        for (; l + 16 < L_; l += 32) {
            float wa = sW[l], wb = sW[l + 16];
            const char* ra = fB + (size_t)l * 2560;
            const char* rb = fB + (size_t)(l + 16) * 2560;
            u16x8 a0 = *reinterpret_cast<const u16x8*>(ra + lane * 16);
            u16x8 a1 = *reinterpret_cast<const u16x8*>(ra + 1024 + lane * 16);
            u16x4 a2 = *reinterpret_cast<const u16x4*>(ra + 2048 + lane * 8);
            u16x8 b0 = *reinterpret_cast<const u16x8*>(rb + lane * 16);
            u16x8 b1 = *reinterpret_cast<const u16x8*>(rb + 1024 + lane * 16);
            u16x4 b2 = *reinterpret_cast<const u16x4*>(rb + 2048 + lane * 8);
            c[0] += wa * bf4_to_f32((u16x4){a0[0],a0[1],a0[2],a0[3]});
            c[1] += wa * bf4_to_f32((u16x4){a0[4],a0[5],a0[6],a0[7]});
            c[2] += wa * bf4_to_f32((u16x4){a1[0],a1[1],a1[2],a1[3]});
            c[3] += wa * bf4_to_f32((u16x4){a1[4],a1[5],a1[6],a1[7]});
            c[4] += wa * bf4_to_f32(a2);
            c[0] += wb * bf4_to_f32((u16x4){b0[0],b0[1],b0[2],b0[3]});
            c[1] += wb * bf4_to_f32((u16x4){b0[4],b0[5],b0[6],b0[7]});
            c[2] += wb * bf4_to_f32((u16x4){b1[0],b1[1],b1[2],b1[3]});
            c[3] += wb * bf4_to_f32((u16x4){b1[4],b1[5],b1[6],b1[7]});
            c[4] += wb * bf4_to_f32(b2);
        }
        if (l < L_) {
            float wa = sW[l];
            const char* ra = fB + (size_t)l * 2560;
            u16x8 a0 = *reinterpret_cast<const u16x8*>(ra + lane * 16);
            u16x8 a1 = *reinterpret_cast<const u16x8*>(ra + 1024 + lane * 16);
            u16x4 a2 = *reinterpret_cast<const u16x4*>(ra + 2048 + lane * 8);
            c[0] += wa * bf4_to_f32((u16x4){a0[0],a0[1],a0[2],a0[3]});
            c[1] += wa * bf4_to_f32((u16x4){a0[4],a0[5],a0[6],a0[7]});
            c[2] += wa * bf4_to_f32((u16x4){a1[0],a1[1],a1[2],a1[3]});
            c[3] += wa * bf4_to_f32((u16x4){a1[4],a1[5],a1[6],a1[7]});
            c[4] += wa * bf4_to_f32(a2);
        }
    } else {
        const float* fB = feat + (size_t)b * L_ * D_;
        int l = wave;
        for (; l + 16 < L_; l += 32) {
            float wa = sW[l], wb = sW[l + 16];
            const float* ra = fB + (size_t)l * D_ + (lane << 2);
            const float* rb = fB + (size_t)(l + 16) * D_ + (lane << 2);
#pragma unroll
            for (int ch = 0; ch < 5; ++ch) {
                c[ch] += wa * *reinterpret_cast<const f32x4*>(ra + ch * 256);
                c[ch] += wb * *reinterpret_cast<const f32x4*>(rb + ch * 256);
            }
        }
        if (l < L_) {
            float wa = sW[l];
            const float* ra = fB + (size_t)l * D_ + (lane << 2);
#pragma unroll
            for (int ch = 0; ch < 5; ++ch)
                c[ch] += wa * *reinterpret_cast<const f32x4*>(ra + ch * 256);
        }
    }

    // ---- final: reduce 16 wave partials, divide by den, write out ----
    float* pc = (float*)smem;   // [16][1280] f32, reuses dbuf region
    if (BF16WS) {
#pragma unroll
        for (int ch = 0; ch < 4; ++ch)
            *reinterpret_cast<f32x4*>(pc + wave * 1280 + (ch >> 1) * 512 + lane * 8 + (ch & 1) * 4) = c[ch];
        *reinterpret_cast<f32x4*>(pc + wave * 1280 + 1024 + lane * 4) = c[4];
    } else {
#pragma unroll
        for (int ch = 0; ch < 5; ++ch)
            *reinterpret_cast<f32x4*>(pc + wave * 1280 + ch * 256 + (lane << 2)) = c[ch];
    }
    __syncthreads();
    if (tid < 320) {
        f32x4 s = (f32x4){0.f, 0.f, 0.f, 0.f};
#pragma unroll
        for (int w = 0; w < 16; ++w)
            s += *reinterpret_cast<const f32x4*>(pc + w * 1280 + (tid << 2));
        float den = 0.f;
#pragma unroll
        for (int i = 0; i < 16; ++i) den += sRed[i];
        s *= (1.f / den);
        *reinterpret_cast<f32x4*>(out + (size_t)b * D_ + (tid << 2)) = s;
    }
}

extern "C" void kernel_launch(void* const* d_in, const int* in_sizes, int n_in,
                              void* d_out, int out_size, void* d_ws, size_t ws_size,
                              hipStream_t stream) {
    const float* feat   = (const float*)d_in[0];
    const float* hidden = (const float*)d_in[1];
    const float* W1     = (const float*)d_in[2];
    const float* b1     = (const float*)d_in[3];
    const float* W2     = (const float*)d_in[4];
    const float* b2     = (const float*)d_in[5];
    const float* Vv     = (const float*)d_in[6];
    // bV (d_in[7]) is a uniform logit shift -> softmax-invariant; skipped.

    char* ws = (char*)d_ws;
    __hip_bfloat16* w1t = (__hip_bfloat16*)(ws);                 // 655360 B
    float* ph           = (float*)(ws + 655360);                 // 262144 B
    __hip_bfloat16* fbf = (__hip_bfloat16*)(ws + 917504);        // 147456000 B
    float* out = (float*)d_out;

    const size_t need = 917504ull + (size_t)B_ * L_ * D_ * 2ull;

    k_prep_w1t<<<(U_ * D_) / 256, 256, 0, stream>>>(W1, w1t);
    k_proj_h  <<<B_, U_, 0, stream>>>(hidden, W2, b1, b2, ph);
    if (ws_size >= need)
        k_fused<1><<<B_, 1024, 0, stream>>>(feat, w1t, ph, Vv, fbf, out);
    else
        k_fused<0><<<B_, 1024, 0, stream>>>(feat, w1t, ph, Vv, fbf, out);
}